// Round 2
// baseline (281.622 us; speedup 1.0000x reference)
//
#include <hip/hip_runtime.h>

// out = (sum_p cos(w_p * phi_p) + (N - C)) / N,  N = next pow2 >= C.
// Pure memory-bound reduction: 256 MiB read, 4 B write.
// R2: manual 4x unroll — 8 independent float4 loads in flight per wave
// before any cos. R1 had VGPR=12 (compiler serialized loads, 2.6 TB/s eff).

#define RBLOCKS 2048   // 8 blocks/CU on 256 CUs; d_ws needs RBLOCKS*4 B = 8 KiB
#define RTHREADS 256

__global__ __launch_bounds__(RTHREADS) void qs_partial_kernel(
    const float* __restrict__ phi, const float* __restrict__ w,
    float* __restrict__ partials, int n4, int n) {
    const float4* __restrict__ p4 = (const float4*)phi;
    const float4* __restrict__ w4 = (const float4*)w;

    float acc = 0.0f;
    const int idx    = blockIdx.x * blockDim.x + threadIdx.x;
    const int stride = gridDim.x * blockDim.x;

    int i = idx;
    // main unrolled loop: 8 independent 16B loads issued back-to-back
    for (; i + 3 * stride < n4; i += 4 * stride) {
        float4 a0 = p4[i];
        float4 a1 = p4[i + stride];
        float4 a2 = p4[i + 2 * stride];
        float4 a3 = p4[i + 3 * stride];
        float4 b0 = w4[i];
        float4 b1 = w4[i + stride];
        float4 b2 = w4[i + 2 * stride];
        float4 b3 = w4[i + 3 * stride];
        acc += __cosf(a0.x * b0.x) + __cosf(a0.y * b0.y)
             + __cosf(a0.z * b0.z) + __cosf(a0.w * b0.w);
        acc += __cosf(a1.x * b1.x) + __cosf(a1.y * b1.y)
             + __cosf(a1.z * b1.z) + __cosf(a1.w * b1.w);
        acc += __cosf(a2.x * b2.x) + __cosf(a2.y * b2.y)
             + __cosf(a2.z * b2.z) + __cosf(a2.w * b2.w);
        acc += __cosf(a3.x * b3.x) + __cosf(a3.y * b3.y)
             + __cosf(a3.z * b3.z) + __cosf(a3.w * b3.w);
    }
    // remainder float4s
    for (; i < n4; i += stride) {
        float4 a = p4[i];
        float4 b = w4[i];
        acc += __cosf(a.x * b.x) + __cosf(a.y * b.y)
             + __cosf(a.z * b.z) + __cosf(a.w * b.w);
    }
    // scalar tail (n not divisible by 4) — single thread, tiny
    if (idx == 0) {
        for (int j = n4 * 4; j < n; ++j) acc += __cosf(phi[j] * w[j]);
    }

    // wave-64 shuffle reduce
    #pragma unroll
    for (int off = 32; off > 0; off >>= 1)
        acc += __shfl_down(acc, off, 64);

    __shared__ float smem[RTHREADS / 64];
    int lane = threadIdx.x & 63;
    int wid  = threadIdx.x >> 6;
    if (lane == 0) smem[wid] = acc;
    __syncthreads();
    if (threadIdx.x == 0) {
        float t = 0.0f;
        #pragma unroll
        for (int k = 0; k < RTHREADS / 64; ++k) t += smem[k];
        partials[blockIdx.x] = t;
    }
}

__global__ __launch_bounds__(1024) void qs_final_kernel(
    const float* __restrict__ partials, float* __restrict__ out,
    int nb, float addend, float inv_n) {
    float acc = 0.0f;
    for (int i = threadIdx.x; i < nb; i += blockDim.x) acc += partials[i];

    #pragma unroll
    for (int off = 32; off > 0; off >>= 1)
        acc += __shfl_down(acc, off, 64);

    __shared__ float smem[1024 / 64];
    int lane = threadIdx.x & 63;
    int wid  = threadIdx.x >> 6;
    if (lane == 0) smem[wid] = acc;
    __syncthreads();
    if (threadIdx.x == 0) {
        float t = 0.0f;
        #pragma unroll
        for (int k = 0; k < 1024 / 64; ++k) t += smem[k];
        out[0] = (t + addend) * inv_n;  // overwrites poisoned d_out every call
    }
}

extern "C" void kernel_launch(void* const* d_in, const int* in_sizes, int n_in,
                              void* d_out, int out_size, void* d_ws, size_t ws_size,
                              hipStream_t stream) {
    const float* phi = (const float*)d_in[0];
    const float* w   = (const float*)d_in[1];
    float* out       = (float*)d_out;
    float* partials  = (float*)d_ws;

    int n  = in_sizes[0];
    int n4 = n >> 2;

    // N = 2^ceil(log2(n))
    long long N = 1;
    while (N < (long long)n) N <<= 1;
    float addend = (float)(N - (long long)n);
    float inv_n  = 1.0f / (float)N;

    qs_partial_kernel<<<RBLOCKS, RTHREADS, 0, stream>>>(phi, w, partials, n4, n);
    qs_final_kernel<<<1, 1024, 0, stream>>>(partials, out, RBLOCKS, addend, inv_n);
}

// Round 3
// 248.472 us; speedup vs baseline: 1.1334x; 1.1334x over previous
//
#include <hip/hip_runtime.h>

// out = (sum_p cos(w_p * phi_p) + (N - C)) / N,  N = next pow2 >= C.
// Pure memory-bound reduction: 256 MiB read, 4 B write.
// R3: non-temporal (nt) streaming loads + block-contiguous spans.
// R1/R2 showed a ~2.6 TB/s service cap even when fully L3-resident;
// hypothesis: the L3-hit path is the cap — stream straight from HBM.

#define RBLOCKS 2048   // 8 blocks/CU; span per block = 64 KiB of each array
#define RTHREADS 256

typedef float v4f __attribute__((ext_vector_type(4)));

__global__ __launch_bounds__(RTHREADS) void qs_partial_kernel(
    const float* __restrict__ phi, const float* __restrict__ w,
    float* __restrict__ partials, int n4, int n) {
    const v4f* __restrict__ p4 = (const v4f*)phi;
    const v4f* __restrict__ w4 = (const v4f*)w;

    // contiguous span per block: better DRAM page + XCD-L2 locality
    const int span  = (n4 + (int)gridDim.x - 1) / (int)gridDim.x;
    const int start = (int)blockIdx.x * span;
    const int lim   = (start + span < n4) ? (start + span) : n4;

    float acc = 0.0f;
    int i = start + (int)threadIdx.x;

    // 2-deep batch: 4 independent nt 16B loads in flight per lane
    for (; i + RTHREADS < lim; i += 2 * RTHREADS) {
        v4f a0 = __builtin_nontemporal_load(p4 + i);
        v4f a1 = __builtin_nontemporal_load(p4 + i + RTHREADS);
        v4f b0 = __builtin_nontemporal_load(w4 + i);
        v4f b1 = __builtin_nontemporal_load(w4 + i + RTHREADS);
        acc += __cosf(a0.x * b0.x) + __cosf(a0.y * b0.y)
             + __cosf(a0.z * b0.z) + __cosf(a0.w * b0.w);
        acc += __cosf(a1.x * b1.x) + __cosf(a1.y * b1.y)
             + __cosf(a1.z * b1.z) + __cosf(a1.w * b1.w);
    }
    for (; i < lim; i += RTHREADS) {
        v4f a = __builtin_nontemporal_load(p4 + i);
        v4f b = __builtin_nontemporal_load(w4 + i);
        acc += __cosf(a.x * b.x) + __cosf(a.y * b.y)
             + __cosf(a.z * b.z) + __cosf(a.w * b.w);
    }
    // scalar tail (n not divisible by 4) — single thread, tiny
    if (blockIdx.x == 0 && threadIdx.x == 0) {
        for (int j = n4 * 4; j < n; ++j) acc += __cosf(phi[j] * w[j]);
    }

    // wave-64 shuffle reduce
    #pragma unroll
    for (int off = 32; off > 0; off >>= 1)
        acc += __shfl_down(acc, off, 64);

    __shared__ float smem[RTHREADS / 64];
    int lane = threadIdx.x & 63;
    int wid  = threadIdx.x >> 6;
    if (lane == 0) smem[wid] = acc;
    __syncthreads();
    if (threadIdx.x == 0) {
        float t = 0.0f;
        #pragma unroll
        for (int k = 0; k < RTHREADS / 64; ++k) t += smem[k];
        partials[blockIdx.x] = t;
    }
}

__global__ __launch_bounds__(1024) void qs_final_kernel(
    const float* __restrict__ partials, float* __restrict__ out,
    int nb, float addend, float inv_n) {
    float acc = 0.0f;
    for (int i = threadIdx.x; i < nb; i += blockDim.x) acc += partials[i];

    #pragma unroll
    for (int off = 32; off > 0; off >>= 1)
        acc += __shfl_down(acc, off, 64);

    __shared__ float smem[1024 / 64];
    int lane = threadIdx.x & 63;
    int wid  = threadIdx.x >> 6;
    if (lane == 0) smem[wid] = acc;
    __syncthreads();
    if (threadIdx.x == 0) {
        float t = 0.0f;
        #pragma unroll
        for (int k = 0; k < 1024 / 64; ++k) t += smem[k];
        out[0] = (t + addend) * inv_n;  // overwrites poisoned d_out every call
    }
}

extern "C" void kernel_launch(void* const* d_in, const int* in_sizes, int n_in,
                              void* d_out, int out_size, void* d_ws, size_t ws_size,
                              hipStream_t stream) {
    const float* phi = (const float*)d_in[0];
    const float* w   = (const float*)d_in[1];
    float* out       = (float*)d_out;
    float* partials  = (float*)d_ws;

    int n  = in_sizes[0];
    int n4 = n >> 2;

    // N = 2^ceil(log2(n))
    long long N = 1;
    while (N < (long long)n) N <<= 1;
    float addend = (float)(N - (long long)n);
    float inv_n  = 1.0f / (float)N;

    qs_partial_kernel<<<RBLOCKS, RTHREADS, 0, stream>>>(phi, w, partials, n4, n);
    qs_final_kernel<<<1, 1024, 0, stream>>>(partials, out, RBLOCKS, addend, inv_n);
}

// Round 4
// 246.102 us; speedup vs baseline: 1.1443x; 1.0096x over previous
//
#include <hip/hip_runtime.h>

// out = (sum_p cos(w_p * phi_p) + (N - C)) / N,  N = next pow2 >= C.
// Pure memory-bound reduction: 256 MiB read, 4 B write.
// R4: 4-deep nt batch (8 loads, 128 B/lane in flight) + 4 independent
// accumulators. R3 (2-deep, 1 acc) reached ~3.7 TB/s eff; fill kernel
// shows the machine does 6.9 TB/s — depth/dep-chain is the suspect.
// NOTE: timed dur_us carries ~170 us of harness restore/poison floor.

#define RBLOCKS 2048   // 8 blocks/CU; span = n4/2048 = 4096 v4f per array
#define RTHREADS 256

typedef float v4f __attribute__((ext_vector_type(4)));

__global__ __launch_bounds__(RTHREADS) void qs_partial_kernel(
    const float* __restrict__ phi, const float* __restrict__ w,
    float* __restrict__ partials, int n4, int n) {
    const v4f* __restrict__ p4 = (const v4f*)phi;
    const v4f* __restrict__ w4 = (const v4f*)w;

    // contiguous span per block: DRAM page + XCD-L2 locality
    const int span  = (n4 + (int)gridDim.x - 1) / (int)gridDim.x;
    const int start = (int)blockIdx.x * span;
    const int lim   = (start + span < n4) ? (start + span) : n4;

    float acc0 = 0.0f, acc1 = 0.0f, acc2 = 0.0f, acc3 = 0.0f;
    int i = start + (int)threadIdx.x;

    // 4-deep batch: 8 independent nt 16B loads in flight per lane,
    // 4 separate accumulator chains so vmcnt waits stay fine-grained.
    for (; i + 3 * RTHREADS < lim; i += 4 * RTHREADS) {
        v4f a0 = __builtin_nontemporal_load(p4 + i);
        v4f a1 = __builtin_nontemporal_load(p4 + i + RTHREADS);
        v4f a2 = __builtin_nontemporal_load(p4 + i + 2 * RTHREADS);
        v4f a3 = __builtin_nontemporal_load(p4 + i + 3 * RTHREADS);
        v4f b0 = __builtin_nontemporal_load(w4 + i);
        v4f b1 = __builtin_nontemporal_load(w4 + i + RTHREADS);
        v4f b2 = __builtin_nontemporal_load(w4 + i + 2 * RTHREADS);
        v4f b3 = __builtin_nontemporal_load(w4 + i + 3 * RTHREADS);
        acc0 += __cosf(a0.x * b0.x) + __cosf(a0.y * b0.y)
              + __cosf(a0.z * b0.z) + __cosf(a0.w * b0.w);
        acc1 += __cosf(a1.x * b1.x) + __cosf(a1.y * b1.y)
              + __cosf(a1.z * b1.z) + __cosf(a1.w * b1.w);
        acc2 += __cosf(a2.x * b2.x) + __cosf(a2.y * b2.y)
              + __cosf(a2.z * b2.z) + __cosf(a2.w * b2.w);
        acc3 += __cosf(a3.x * b3.x) + __cosf(a3.y * b3.y)
              + __cosf(a3.z * b3.z) + __cosf(a3.w * b3.w);
    }
    // remainder float4s (1-deep)
    for (; i < lim; i += RTHREADS) {
        v4f a = __builtin_nontemporal_load(p4 + i);
        v4f b = __builtin_nontemporal_load(w4 + i);
        acc0 += __cosf(a.x * b.x) + __cosf(a.y * b.y)
              + __cosf(a.z * b.z) + __cosf(a.w * b.w);
    }
    // scalar tail (n not divisible by 4) — single thread, tiny
    if (blockIdx.x == 0 && threadIdx.x == 0) {
        for (int j = n4 * 4; j < n; ++j) acc0 += __cosf(phi[j] * w[j]);
    }

    float acc = (acc0 + acc1) + (acc2 + acc3);

    // wave-64 shuffle reduce
    #pragma unroll
    for (int off = 32; off > 0; off >>= 1)
        acc += __shfl_down(acc, off, 64);

    __shared__ float smem[RTHREADS / 64];
    int lane = threadIdx.x & 63;
    int wid  = threadIdx.x >> 6;
    if (lane == 0) smem[wid] = acc;
    __syncthreads();
    if (threadIdx.x == 0) {
        float t = 0.0f;
        #pragma unroll
        for (int k = 0; k < RTHREADS / 64; ++k) t += smem[k];
        partials[blockIdx.x] = t;
    }
}

__global__ __launch_bounds__(1024) void qs_final_kernel(
    const float* __restrict__ partials, float* __restrict__ out,
    int nb, float addend, float inv_n) {
    float acc = 0.0f;
    for (int i = threadIdx.x; i < nb; i += blockDim.x) acc += partials[i];

    #pragma unroll
    for (int off = 32; off > 0; off >>= 1)
        acc += __shfl_down(acc, off, 64);

    __shared__ float smem[1024 / 64];
    int lane = threadIdx.x & 63;
    int wid  = threadIdx.x >> 6;
    if (lane == 0) smem[wid] = acc;
    __syncthreads();
    if (threadIdx.x == 0) {
        float t = 0.0f;
        #pragma unroll
        for (int k = 0; k < 1024 / 64; ++k) t += smem[k];
        out[0] = (t + addend) * inv_n;  // overwrites poisoned d_out every call
    }
}

extern "C" void kernel_launch(void* const* d_in, const int* in_sizes, int n_in,
                              void* d_out, int out_size, void* d_ws, size_t ws_size,
                              hipStream_t stream) {
    const float* phi = (const float*)d_in[0];
    const float* w   = (const float*)d_in[1];
    float* out       = (float*)d_out;
    float* partials  = (float*)d_ws;

    int n  = in_sizes[0];
    int n4 = n >> 2;

    // N = 2^ceil(log2(n))
    long long N = 1;
    while (N < (long long)n) N <<= 1;
    float addend = (float)(N - (long long)n);
    float inv_n  = 1.0f / (float)N;

    qs_partial_kernel<<<RBLOCKS, RTHREADS, 0, stream>>>(phi, w, partials, n4, n);
    qs_final_kernel<<<1, 1024, 0, stream>>>(partials, out, RBLOCKS, addend, inv_n);
}